// Round 8
// baseline (23550.441 us; speedup 1.0000x reference)
//
#include <hip/hip_runtime.h>

// ============================================================================
// GRU autoencoder, single persistent kernel, MI355X (gfx950).  Round 14:
// round-13 structure (round-6 data path + all-wave epilogue, verified
// 22.0 ms) with a COUNTER-AGGREGATED SINGLE-HOP BARRIER:
//   - at epoch end, each block's tid0 does one atomicFetchAdd(cnt,1,RELEASE);
//     the block that sees old == 256*e - 1 is the last finisher and
//     release-publishes gep = e directly.  Consumers poll only gep.
//   - removes round-13's root-DETECT polling stage (~0.5-1.5 us of L3
//     round-trip + poll-period quantization) from every epoch's critical
//     path; the last finisher learns it is last from its add's return
//     value, in-line, without polling anyone.
//   - counter is monotone (no reset): after epoch e completes globally,
//     cnt == 256*e (epochs are phase-ordered by the gep wait).
//   - visibility: each block's RELEASE add orders its agent-scope ring
//     stores before the increment; cnt==256*e implies all stores visible;
//     publisher's gep store is program-ordered after its add.  Consumers
//     use the same relaxed-poll + agent-scope data loads as rounds 6-13.
// ============================================================================

#define SC_AGT __HIP_MEMORY_SCOPE_AGENT

typedef _Float16 half8 __attribute__((ext_vector_type(8)));
typedef float floatx4 __attribute__((ext_vector_type(4)));

union H8 { unsigned long long q[2]; half8 h; uint4 u4; };
union HU { _Float16 f; unsigned short u; };

// ---- workspace layout (bytes) ----
static constexpr size_t OFF_CNT   = 0;                        // 1 * 64B line
static constexpr size_t OFF_GEP   = 16384;                    // 1 * 64B line
static constexpr size_t OFF_Z     = 16448;                    // 64*128*4
static constexpr size_t OFF_GXC   = OFF_Z + 64 * 128 * 4;     // 64*1536*4
static constexpr size_t OFF_H0    = OFF_GXC + 64 * 1536 * 4;  // 2*64*512*2 each
static constexpr size_t OFF_H1    = OFF_H0 + 2 * 64 * 512 * 2;
static constexpr size_t OFF_G0    = OFF_H1 + 2 * 64 * 512 * 2;
static constexpr size_t OFF_G1    = OFF_G0 + 2 * 64 * 512 * 2;
static constexpr size_t OFF_LWP   = OFF_G1 + 2 * 64 * 512 * 2; // 64*512*2
static constexpr size_t OFF_WF    = OFF_LWP + 64 * 512 * 2;
// W-fragment store: unit = (gate,hcb,kc) = 2KB (hi plane 1KB + lo plane 1KB)
// layer unit counts: L0 1728, L1 3072, L2 1536, L3 3072  (total ~18.4 MB)

static constexpr int E_PREP    = 1;
static constexpr int E_ENC_BEG = 2;     // u = e-2, u in [0,1024]
static constexpr int E_ENC_END = 1026;
static constexpr int E_Z       = 1027;
static constexpr int E_GXC     = 1028;
static constexpr int E_DEC_BEG = 1029;  // v = e-1029, v in [0,1025]
static constexpr int E_LAST    = 2054;

__device__ __forceinline__ unsigned long long ald64(const void* p) {
  return __hip_atomic_load((const unsigned long long*)p, __ATOMIC_RELAXED, SC_AGT);
}
__device__ __forceinline__ int ald32(const int* p) {
  return __hip_atomic_load(p, __ATOMIC_RELAXED, SC_AGT);
}
__device__ __forceinline__ void ast16(void* p, unsigned short v) {
  __hip_atomic_store((unsigned short*)p, v, __ATOMIC_RELAXED, SC_AGT);
}
__device__ __forceinline__ void ast32u(void* p, unsigned int v) {
  __hip_atomic_store((unsigned int*)p, v, __ATOMIC_RELAXED, SC_AGT);
}
__device__ __forceinline__ void astf(float* p, float v) {
  __hip_atomic_store(p, v, __ATOMIC_RELAXED, SC_AGT);
}

__device__ __forceinline__ float sigm(float x) { return 1.f / (1.f + __expf(-x)); }
__device__ __forceinline__ float tanh_f(float x) {
  x = fminf(fmaxf(x, -30.f), 30.f);
  const float e2 = __expf(2.f * x);
  return (e2 - 1.f) / (e2 + 1.f);
}

#define MFMA(a, b, c) __builtin_amdgcn_mfma_f32_16x16x32_f16((a), (b), (c), 0, 0, 0)

// barrier wait: poll the single global epoch counter (wave-uniform address
// -> one L3 request per wave per iteration).
__device__ __forceinline__ void pollwait_gep(const int* gep, int target) {
  for (;;) {
    if (ald32(gep) >= target) break;
    __builtin_amdgcn_s_sleep(1);
  }
  asm volatile("" ::: "memory");
}

// One GRU step partial-GEMM for this wave's K-slice (round-1/round-6
// verbatim: INLINE weight loads -- the verified data path).
__device__ __forceinline__ void tick_partials(
    const char* __restrict__ wf,
    int g0u, int g1u, int g2u, int g3u,
    int nk0, int nk1, int nk2, int nk3,
    int kc0, int kccnt, int hsplit,
    const float* __restrict__ xs,
    const _Float16* __restrict__ ax,
    const _Float16* __restrict__ ah,
    bool hvalid, int hcb, int lane,
    float* __restrict__ partsW) {
  const int quad = lane >> 4;
  H8 A[8];
#pragma unroll
  for (int c = 0; c < 8; ++c) {
    A[c].q[0] = 0ull;
    A[c].q[1] = 0ull;
    if (c < kccnt) {
      const int kc = kc0 + c;
      if (kc < hsplit) {
        if (xs) {
          const float* p = xs + kc * 32 + quad * 8;
          const float4 f0 = *(const float4*)p;
          const float4 f1 = *(const float4*)(p + 4);
          H8 t;
          t.h[0] = (_Float16)f0.x; t.h[1] = (_Float16)f0.y;
          t.h[2] = (_Float16)f0.z; t.h[3] = (_Float16)f0.w;
          t.h[4] = (_Float16)f1.x; t.h[5] = (_Float16)f1.y;
          t.h[6] = (_Float16)f1.z; t.h[7] = (_Float16)f1.w;
          A[c] = t;
        } else {
          const _Float16* p = ax + kc * 32 + quad * 8;
          A[c].q[0] = ald64(p);
          A[c].q[1] = ald64(p + 4);
        }
      } else if (hvalid) {
        const _Float16* p = ah + (kc - hsplit) * 32 + quad * 8;
        A[c].q[0] = ald64(p);
        A[c].q[1] = ald64(p + 4);
      }
    }
  }
  floatx4 ar = {0.f, 0.f, 0.f, 0.f};
  floatx4 az = ar, axn = ar, ahn = ar;
  const size_t lb = (size_t)lane * 16;
#pragma unroll
  for (int c = 0; c < 8; ++c) {
    if (c < kccnt) {
      const int kc = kc0 + c;
      const bool inH = (kc >= hsplit);
      if (!inH || hvalid) {
        {
          const char* b = wf + (size_t)(g0u + hcb * nk0 + kc) * 2048 + lb;
          H8 whi, wlo;
          whi.u4 = *(const uint4*)b;
          wlo.u4 = *(const uint4*)(b + 1024);
          ar = MFMA(A[c].h, whi.h, ar);
          ar = MFMA(A[c].h, wlo.h, ar);
        }
        {
          const char* b = wf + (size_t)(g1u + hcb * nk1 + kc) * 2048 + lb;
          H8 whi, wlo;
          whi.u4 = *(const uint4*)b;
          wlo.u4 = *(const uint4*)(b + 1024);
          az = MFMA(A[c].h, whi.h, az);
          az = MFMA(A[c].h, wlo.h, az);
        }
        if (!inH) {
          const char* b = wf + (size_t)(g2u + hcb * nk2 + kc) * 2048 + lb;
          H8 whi, wlo;
          whi.u4 = *(const uint4*)b;
          wlo.u4 = *(const uint4*)(b + 1024);
          axn = MFMA(A[c].h, whi.h, axn);
          axn = MFMA(A[c].h, wlo.h, axn);
        } else {
          const char* b = wf + (size_t)(g3u + hcb * nk3 + (kc - hsplit)) * 2048 + lb;
          H8 whi, wlo;
          whi.u4 = *(const uint4*)b;
          wlo.u4 = *(const uint4*)(b + 1024);
          ahn = MFMA(A[c].h, whi.h, ahn);
          ahn = MFMA(A[c].h, wlo.h, ahn);
        }
      }
    }
  }
  const int m = lane & 15;
#pragma unroll
  for (int i = 0; i < 4; ++i) {
    const int idx = (quad * 4 + i) * 16 + m;
    partsW[0 * 256 + idx] = ar[i];
    partsW[1 * 256 + idx] = az[i];
    partsW[2 * 256 + idx] = axn[i];
    partsW[3 * 256 + idx] = ahn[i];
  }
}

extern "C" __global__ void __launch_bounds__(256, 1) gru_ae_kernel(
    const float* __restrict__ x,
    const float* __restrict__ eW0i, const float* __restrict__ eW0h,
    const float* __restrict__ eb0i, const float* __restrict__ eb0h,
    const float* __restrict__ eW1i, const float* __restrict__ eW1h,
    const float* __restrict__ eb1i, const float* __restrict__ eb1h,
    const float* __restrict__ elW, const float* __restrict__ elb,
    const float* __restrict__ dW0i, const float* __restrict__ dW0h,
    const float* __restrict__ db0i, const float* __restrict__ db0h,
    const float* __restrict__ dW1i, const float* __restrict__ dW1h,
    const float* __restrict__ db1i, const float* __restrict__ db1h,
    const float* __restrict__ dlW, const float* __restrict__ dlb,
    float* __restrict__ out, char* __restrict__ ws) {
  const int tid = threadIdx.x, bid = blockIdx.x;
  const int lane = tid & 63, w = tid >> 6;
  const int quad = lane >> 4, m = lane & 15;
  const bool isP0 = bid < 128;
  const int pb = isP0 ? bid : bid - 128;
  const int rb = pb >> 5, hcb = pb & 31;

  int* cnt = (int*)(ws + OFF_CNT);
  int* gep = (int*)(ws + OFF_GEP);
  float* zbuf = (float*)(ws + OFF_Z);
  float* gxc = (float*)(ws + OFF_GXC);
  _Float16* h0r = (_Float16*)(ws + OFF_H0);
  _Float16* h1r = (_Float16*)(ws + OFF_H1);
  _Float16* g0r = (_Float16*)(ws + OFF_G0);
  _Float16* g1r = (_Float16*)(ws + OFF_G1);
  _Float16* lWp = (_Float16*)(ws + OFF_LWP);
  const char* wfb = ws + OFF_WF;
  const char* wf0 = wfb;
  const char* wf1 = wfb + (size_t)1728 * 2048;
  const char* wf2 = wfb + (size_t)(1728 + 3072) * 2048;
  const char* wf3 = wfb + (size_t)(1728 + 3072 + 1536) * 2048;

  __shared__ float parts[4][4][256];
  __shared__ float outp[4][64];

  // per-thread epilogue state: wave w owns output row-slot i=w
  float hold_s = 0.f;
  float br = 0.f, bz = 0.f, bx = 0.f, bh = 0.f;
  float gxr_s = 0.f, gxz_s = 0.f, gxn_s = 0.f;

  for (int e = E_PREP; e <= E_LAST; ++e) {
    if (e > E_PREP) {
      if (w == 0) pollwait_gep(gep, e - 1);
      __syncthreads();  // release other waves once w0 has seen the epoch
    }

    // ---------------- WORK (all waves) ----------------
    if (e == E_PREP) {
      // pack weights: fp16 hi/lo planes, MFMA-fragment ordered
      const int uend[4] = {1728, 4800, 6336, 9408};
      const int gub_[4][4] = {{0, 576, 1152, 1216}, {0, 1024, 2048, 2560},
                              {0, 512, 1024, 1024}, {0, 1024, 2048, 2560}};
      const int nkc_[4][4] = {{18, 18, 2, 16}, {32, 32, 16, 16},
                              {16, 16, 0, 16}, {32, 32, 16, 16}};
      const size_t wbL[4] = {0, (size_t)1728 * 2048, (size_t)4800 * 2048,
                             (size_t)6336 * 2048};
      const int wgid = bid * 4 + w;
      for (int unit = wgid; unit < 9408; unit += 1024) {
        int L = 0, lu = unit;
        if (unit >= uend[2]) { L = 3; lu = unit - uend[2]; }
        else if (unit >= uend[1]) { L = 2; lu = unit - uend[1]; }
        else if (unit >= uend[0]) { L = 1; lu = unit - uend[0]; }
        int g;
        if (lu < gub_[L][1]) g = 0;
        else if (lu < gub_[L][2]) g = 1;
        else if (nkc_[L][2] > 0 && lu < gub_[L][3]) g = 2;
        else g = 3;
        const int r2 = lu - gub_[L][g];
        const int nk = nkc_[L][g];
        const int hcbp = r2 / nk, kcp = r2 % nk;
        const int colp = hcbp * 16 + m;
        const float *Wi, *Wh;
        int Din;
        if (L == 0)      { Wi = eW0i; Wh = eW0h; Din = 64; }
        else if (L == 1) { Wi = eW1i; Wh = eW1h; Din = 512; }
        else if (L == 2) { Wi = nullptr; Wh = dW0h; Din = 0; }
        else             { Wi = dW1i; Wh = dW1h; Din = 512; }
        char* ub = (char*)(ws + OFF_WF) + wbL[L] + (size_t)lu * 2048 + lane * 16;
#pragma unroll
        for (int jj = 0; jj < 4; ++jj) {
          unsigned int hiw = 0, low = 0;
#pragma unroll
          for (int j2 = 0; j2 < 2; ++j2) {
            const int j = jj * 2 + j2;
            const int k = kcp * 32 + quad * 8 + j;
            float wv;
            if (g <= 1) {
              if (Wi && k < Din) wv = Wi[(size_t)(g * 512 + colp) * Din + k];
              else wv = Wh[(size_t)(g * 512 + colp) * 512 + (k - (Wi ? Din : 0))];
            } else if (g == 2) {
              wv = Wi[(size_t)(1024 + colp) * Din + k];
            } else {
              wv = Wh[(size_t)(1024 + colp) * 512 + k];
            }
            HU hi, lo;
            hi.f = (_Float16)wv;
            lo.f = (_Float16)(wv - (float)hi.f);
            hiw |= ((unsigned int)hi.u) << (16 * j2);
            low |= ((unsigned int)lo.u) << (16 * j2);
          }
          ast32u(ub + jj * 4, hiw);
          ast32u(ub + 1024 + jj * 4, low);
        }
      }
      // pack final-linear weight fp16
      const int gid = bid * 256 + tid;
      if (gid < 32768) {
        HU cv;
        cv.f = (_Float16)dlW[gid];
        ast16(lWp + gid, cv.u);
      }
    } else if (e <= E_ENC_END) {
      const int u = e - E_ENC_BEG;
      if (e == E_ENC_BEG) {
        const int colg = hcb * 16 + m;
        if (isP0) {
          br = eb0i[colg] + eb0h[colg];
          bz = eb0i[512 + colg] + eb0h[512 + colg];
          bx = eb0i[1024 + colg];
          bh = eb0h[1024 + colg];
        } else {
          br = eb1i[colg] + eb1h[colg];
          bz = eb1i[512 + colg] + eb1h[512 + colg];
          bx = eb1i[1024 + colg];
          bh = eb1h[1024 + colg];
        }
        hold_s = 0.f;
      }
      if (isP0) {
        if (u <= 1023) {
          const int t = u;
          const float* xs = x + ((size_t)t * 64 + rb * 16 + m) * 64;
          const _Float16* ah = h0r + (size_t)((t - 1) & 1) * 32768 + (rb * 16 + m) * 512;
          const int kc0 = (w == 0) ? 0 : (w == 1) ? 5 : (w == 2) ? 10 : 14;
          const int cnt_ = (w < 2) ? 5 : 4;
          tick_partials(wf0, 0, 576, 1152, 1216, 18, 18, 2, 16, kc0, cnt_, 2,
                        xs, nullptr, ah, t >= 1, hcb, lane, &parts[w][0][0]);
        }
      } else {
        if (u >= 1) {
          const int t = u - 1;
          const _Float16* ax = h0r + (size_t)(t & 1) * 32768 + (rb * 16 + m) * 512;
          const _Float16* ah = h1r + (size_t)((t - 1) & 1) * 32768 + (rb * 16 + m) * 512;
          tick_partials(wf1, 0, 1024, 2048, 2560, 32, 32, 16, 16, w * 8, 8, 16,
                        nullptr, ax, ah, t >= 1, hcb, lane, &parts[w][0][0]);
        }
      }
    } else if (e == E_Z) {
      const int b = bid >> 2, e0 = (bid & 3) * 32;
      float acc = 0.f;
      if (lane < 32) {
        const _Float16* hsrc = h1r + (size_t)1 * 32768 + b * 512;  // h1[1023]
        const float* lwrow = elW + (size_t)(e0 + lane) * 512;
        for (int ch = 0; ch < 16; ++ch) {
          const int k = w * 128 + ch * 8;
          H8 a;
          a.q[0] = ald64(hsrc + k);
          a.q[1] = ald64(hsrc + k + 4);
          const float4 l0 = *(const float4*)(lwrow + k);
          const float4 l1 = *(const float4*)(lwrow + k + 4);
          acc += (float)a.h[0] * l0.x + (float)a.h[1] * l0.y +
                 (float)a.h[2] * l0.z + (float)a.h[3] * l0.w +
                 (float)a.h[4] * l1.x + (float)a.h[5] * l1.y +
                 (float)a.h[6] * l1.z + (float)a.h[7] * l1.w;
        }
      }
      outp[w][lane] = acc;
    } else if (e == E_GXC) {
      const int b = bid & 63, cb = (bid >> 6) * 384;
      for (int idx = w * 64 + lane; idx < 384; idx += 256) {
        const int c = cb + idx;
        float acc = db0i[c];
        const float* zr = zbuf + b * 128;
        const float* wr = dW0i + (size_t)c * 128;
        for (int k = 0; k < 128; ++k) acc += zr[k] * wr[k];
        astf(&gxc[(size_t)b * 1536 + c], acc);
      }
    } else {
      const int v = e - E_DEC_BEG;
      if (e == E_DEC_BEG) {
        const int colg = hcb * 16 + m;
        if (isP0) {
          br = db0h[colg];
          bz = db0h[512 + colg];
          bx = 0.f;
          bh = db0h[1024 + colg];
          // per-thread gx scalars for this thread's epilogue row (i = w)
          const int row0 = rb * 16 + quad * 4 + w;
          gxr_s = gxc[(size_t)row0 * 1536 + colg];
          gxz_s = gxc[(size_t)row0 * 1536 + 512 + colg];
          gxn_s = gxc[(size_t)row0 * 1536 + 1024 + colg];
        } else {
          br = db1i[colg] + db1h[colg];
          bz = db1i[512 + colg] + db1h[512 + colg];
          bx = db1i[1024 + colg];
          bh = db1h[1024 + colg];
        }
        hold_s = 0.f;
      }
      if (isP0) {
        if (v <= 1023) {
          const int t = v;
          const _Float16* ah = g0r + (size_t)((t - 1) & 1) * 32768 + (rb * 16 + m) * 512;
          tick_partials(wf2, 0, 512, 0, 1024, 16, 16, 0, 16, w * 4, 4, 0,
                        nullptr, nullptr, ah, t >= 1, hcb, lane, &parts[w][0][0]);
        }
        if (pb < 64 && v >= 2) {
          // final linear partials: out[t2][b=pb][i=lane], K split by wave
          const int t2 = v - 2;
          const _Float16* gsrc = g1r + (size_t)(t2 & 1) * 32768 + pb * 512;
          const _Float16* lrow = lWp + (size_t)lane * 512;
          float acc = 0.f;
          for (int ch = 0; ch < 16; ++ch) {
            const int k = w * 128 + ch * 8;
            H8 a, lw;
            a.q[0] = ald64(gsrc + k);
            a.q[1] = ald64(gsrc + k + 4);
            lw.u4 = *(const uint4*)(lrow + k);
#pragma unroll
            for (int j = 0; j < 8; ++j) acc += (float)a.h[j] * (float)lw.h[j];
          }
          outp[w][lane] = acc;
        }
      } else {
        if (v >= 1 && v <= 1024) {
          const int t = v - 1;
          const _Float16* ax = g0r + (size_t)(t & 1) * 32768 + (rb * 16 + m) * 512;
          const _Float16* ah = g1r + (size_t)((t - 1) & 1) * 32768 + (rb * 16 + m) * 512;
          tick_partials(wf3, 0, 1024, 2048, 2560, 32, 32, 16, 16, w * 8, 8, 16,
                        nullptr, ax, ah, t >= 1, hcb, lane, &parts[w][0][0]);
        }
      }
    }

    __syncthreads();  // bar1: all partials in LDS, all waves' stores drained

    // -------- EPILOGUE (all waves; wave w owns row-slot i=w) --------
    if (e >= E_ENC_BEG && e <= E_ENC_END) {
      const int u = e - E_ENC_BEG;
      const bool doep = isP0 ? (u <= 1023) : (u >= 1);
      if (doep) {
        const int idx = (quad * 4 + w) * 16 + m;
        const float sr = parts[0][0][idx] + parts[1][0][idx] +
                         parts[2][0][idx] + parts[3][0][idx];
        const float sz = parts[0][1][idx] + parts[1][1][idx] +
                         parts[2][1][idx] + parts[3][1][idx];
        const float sx = parts[0][2][idx] + parts[1][2][idx] +
                         parts[2][2][idx] + parts[3][2][idx];
        const float sh = parts[0][3][idx] + parts[1][3][idx] +
                         parts[2][3][idx] + parts[3][3][idx];
        const float r = sigm(sr + br);
        const float z = sigm(sz + bz);
        const float n = tanh_f(sx + bx + r * (sh + bh));
        const float hh = (1.f - z) * n + z * hold_s;
        hold_s = hh;
        _Float16* ring = isP0 ? (h0r + (size_t)(u & 1) * 32768)
                              : (h1r + (size_t)((u - 1) & 1) * 32768);
        HU cv;
        cv.f = (_Float16)hh;
        ast16(ring + (rb * 16 + quad * 4 + w) * 512 + hcb * 16 + m, cv.u);
      }
    } else if (e == E_Z) {
      if (w == 0 && lane < 32) {
        const int b = bid >> 2, e0 = (bid & 3) * 32;
        const float s = outp[0][lane] + outp[1][lane] + outp[2][lane] +
                        outp[3][lane] + elb[e0 + lane];
        astf(&zbuf[b * 128 + e0 + lane], s);
      }
    } else if (e >= E_DEC_BEG) {
      const int v = e - E_DEC_BEG;
      if (isP0) {
        if (v <= 1023) {
          const int idx = (quad * 4 + w) * 16 + m;
          const float sr = parts[0][0][idx] + parts[1][0][idx] +
                           parts[2][0][idx] + parts[3][0][idx];
          const float sz = parts[0][1][idx] + parts[1][1][idx] +
                           parts[2][1][idx] + parts[3][1][idx];
          const float sh = parts[0][3][idx] + parts[1][3][idx] +
                           parts[2][3][idx] + parts[3][3][idx];
          const float r = sigm(sr + gxr_s + br);
          const float z = sigm(sz + gxz_s + bz);
          const float n = tanh_f(gxn_s + r * (sh + bh));
          const float hh = (1.f - z) * n + z * hold_s;
          hold_s = hh;
          HU cv;
          cv.f = (_Float16)hh;
          ast16(g0r + (size_t)(v & 1) * 32768 +
                    (rb * 16 + quad * 4 + w) * 512 + hcb * 16 + m,
                cv.u);
        }
        if (w == 0 && pb < 64 && v >= 2) {
          const int t2 = v - 2;
          const float s = outp[0][lane] + outp[1][lane] + outp[2][lane] +
                          outp[3][lane] + dlb[lane];
          astf(&out[((size_t)t2 * 64 + pb) * 64 + lane], s);
        }
      } else {
        if (v >= 1 && v <= 1024) {
          const int idx = (quad * 4 + w) * 16 + m;
          const float sr = parts[0][0][idx] + parts[1][0][idx] +
                           parts[2][0][idx] + parts[3][0][idx];
          const float sz = parts[0][1][idx] + parts[1][1][idx] +
                           parts[2][1][idx] + parts[3][1][idx];
          const float sx = parts[0][2][idx] + parts[1][2][idx] +
                           parts[2][2][idx] + parts[3][2][idx];
          const float sh = parts[0][3][idx] + parts[1][3][idx] +
                           parts[2][3][idx] + parts[3][3][idx];
          const float r = sigm(sr + br);
          const float z = sigm(sz + bz);
          const float n = tanh_f(sx + bx + r * (sh + bh));
          const float hh = (1.f - z) * n + z * hold_s;
          hold_s = hh;
          HU cv;
          cv.f = (_Float16)hh;
          ast16(g1r + (size_t)((v - 1) & 1) * 32768 +
                    (rb * 16 + quad * 4 + w) * 512 + hcb * 16 + m,
                cv.u);
        }
      }
    }

    __syncthreads();  // bar2: drain ALL waves' epilogue stores + LDS reuse

    if (tid == 0) {
      // single-hop barrier arrival: RELEASE add orders this block's ring
      // stores (drained at bar2) before the increment becomes visible.
      const int old =
          __hip_atomic_fetch_add(cnt, 1, __ATOMIC_RELEASE, SC_AGT);
      if (old == 256 * e - 1) {
        // last finisher of epoch e publishes it directly -- no root poll.
        __hip_atomic_store(gep, e, __ATOMIC_RELEASE, SC_AGT);
      }
    }
  }
}

extern "C" void kernel_launch(void* const* d_in, const int* in_sizes, int n_in,
                              void* d_out, int out_size, void* d_ws, size_t ws_size,
                              hipStream_t stream) {
  (void)in_sizes; (void)n_in; (void)out_size; (void)ws_size;
  hipMemsetAsync(d_ws, 0, 16448, stream);  // zero arrival counter + gepoch
  hipLaunchKernelGGL(gru_ae_kernel, dim3(256), dim3(256), 0, stream,
                     (const float*)d_in[0],
                     (const float*)d_in[1], (const float*)d_in[2],
                     (const float*)d_in[3], (const float*)d_in[4],
                     (const float*)d_in[5], (const float*)d_in[6],
                     (const float*)d_in[7], (const float*)d_in[8],
                     (const float*)d_in[9], (const float*)d_in[10],
                     (const float*)d_in[11], (const float*)d_in[12],
                     (const float*)d_in[13], (const float*)d_in[14],
                     (const float*)d_in[15], (const float*)d_in[16],
                     (const float*)d_in[17], (const float*)d_in[18],
                     (const float*)d_in[19], (const float*)d_in[20],
                     (float*)d_out, (char*)d_ws);
}

// Round 10
// 18477.582 us; speedup vs baseline: 1.2745x; 1.2745x over previous
//
#include <hip/hip_runtime.h>

// ============================================================================
// GRU autoencoder, single persistent kernel, MI355X (gfx950).  Round 16:
// round-13 base (root-aggregated gep barrier + all-wave epilogue, verified
// 22.0 ms) with HI-PLANE-ONLY WEIGHTS:
//   - the fp16 lo (residual) plane is no longer read: 24 instead of 48
//     weight loads and MFMAs per stage-1 tick.  hi/lo live in separate
//     1KB halves of each 2KB unit, so lo cache lines are never fetched --
//     per-XCD weight working set ~4.8MB -> ~2.4MB, which fits the 4MB L2:
//     weight loads drop from L3 (~600-900cy) to L2 (~200cy) latency.
//   - justified: the h-state ring is ALREADY fp16, so A-operands carry
//     fp16 quantization everywhere; the lo-plane only corrected weight
//     quantization of the same order (~2^-11).  absmax headroom is 4.5x.
//   - register-array weight prefetch permanently closed (r7/r9/r11/r15
//     fail bit-identically: restrict-UB and/or union-TBAA disconnects the
//     split producer/consumer W path; inline loads are the verified path).
//   - pack format unchanged (lo planes still written at E_PREP, unread).
// ============================================================================

#define SC_AGT __HIP_MEMORY_SCOPE_AGENT

typedef _Float16 half8 __attribute__((ext_vector_type(8)));
typedef float floatx4 __attribute__((ext_vector_type(4)));

union H8 { unsigned long long q[2]; half8 h; uint4 u4; };
union HU { _Float16 f; unsigned short u; };

// ---- workspace layout (bytes) ----
static constexpr size_t OFF_FLAGS = 0;                        // 256 * 64B lines
static constexpr size_t OFF_GEP   = 16384;                    // 1 * 64B line
static constexpr size_t OFF_Z     = 16448;                    // 64*128*4
static constexpr size_t OFF_GXC   = OFF_Z + 64 * 128 * 4;     // 64*1536*4
static constexpr size_t OFF_H0    = OFF_GXC + 64 * 1536 * 4;  // 2*64*512*2 each
static constexpr size_t OFF_H1    = OFF_H0 + 2 * 64 * 512 * 2;
static constexpr size_t OFF_G0    = OFF_H1 + 2 * 64 * 512 * 2;
static constexpr size_t OFF_G1    = OFF_G0 + 2 * 64 * 512 * 2;
static constexpr size_t OFF_LWP   = OFF_G1 + 2 * 64 * 512 * 2; // 64*512*2
static constexpr size_t OFF_WF    = OFF_LWP + 64 * 512 * 2;
// W-fragment store: unit = (gate,hcb,kc) = 2KB (hi plane 1KB + lo plane 1KB)
// layer unit counts: L0 1728, L1 3072, L2 1536, L3 3072  (total ~18.4 MB)

static constexpr int E_PREP    = 1;
static constexpr int E_ENC_BEG = 2;     // u = e-2, u in [0,1024]
static constexpr int E_ENC_END = 1026;
static constexpr int E_Z       = 1027;
static constexpr int E_GXC     = 1028;
static constexpr int E_DEC_BEG = 1029;  // v = e-1029, v in [0,1025]
static constexpr int E_LAST    = 2054;

__device__ __forceinline__ unsigned long long ald64(const void* p) {
  return __hip_atomic_load((const unsigned long long*)p, __ATOMIC_RELAXED, SC_AGT);
}
__device__ __forceinline__ int ald32(const int* p) {
  return __hip_atomic_load(p, __ATOMIC_RELAXED, SC_AGT);
}
__device__ __forceinline__ void ast16(void* p, unsigned short v) {
  __hip_atomic_store((unsigned short*)p, v, __ATOMIC_RELAXED, SC_AGT);
}
__device__ __forceinline__ void ast32u(void* p, unsigned int v) {
  __hip_atomic_store((unsigned int*)p, v, __ATOMIC_RELAXED, SC_AGT);
}
__device__ __forceinline__ void astf(float* p, float v) {
  __hip_atomic_store(p, v, __ATOMIC_RELAXED, SC_AGT);
}

__device__ __forceinline__ float sigm(float x) { return 1.f / (1.f + __expf(-x)); }
__device__ __forceinline__ float tanh_f(float x) {
  x = fminf(fmaxf(x, -30.f), 30.f);
  const float e2 = __expf(2.f * x);
  return (e2 - 1.f) / (e2 + 1.f);
}

#define MFMA(a, b, c) __builtin_amdgcn_mfma_f32_16x16x32_f16((a), (b), (c), 0, 0, 0)

// root barrier wait (block 0, wave 0 only): lane i polls block flags i,
// i+64, i+128, i+192 -- each flag on its own 64B line (flags[bid*16]).
__device__ __forceinline__ void pollwait(const int* flags, int target) {
  const int lane = threadIdx.x & 63;
  for (;;) {
    const int v0 = ald32(flags + (size_t)lane * 16);
    const int v1 = ald32(flags + (size_t)(64 + lane) * 16);
    const int v2 = ald32(flags + (size_t)(128 + lane) * 16);
    const int v3 = ald32(flags + (size_t)(192 + lane) * 16);
    const bool ok = (v0 >= target) && (v1 >= target) && (v2 >= target) &&
                    (v3 >= target);
    if (__ballot(ok) == ~0ull) break;
    __builtin_amdgcn_s_sleep(2);
  }
  asm volatile("" ::: "memory");
}

// non-root barrier wait: poll the single global epoch counter (wave-uniform
// address -> one L3 request per wave per iteration).
__device__ __forceinline__ void pollwait_gep(const int* gep, int target) {
  for (;;) {
    if (ald32(gep) >= target) break;
    __builtin_amdgcn_s_sleep(1);
  }
  asm volatile("" ::: "memory");
}

// One GRU step partial-GEMM for this wave's K-slice.  Round-6-verbatim
// structure (INLINE weight loads) but HI-PLANE ONLY: one load + one MFMA
// per gate per kc (lo residual plane unread).
__device__ __forceinline__ void tick_partials(
    const char* __restrict__ wf,
    int g0u, int g1u, int g2u, int g3u,
    int nk0, int nk1, int nk2, int nk3,
    int kc0, int kccnt, int hsplit,
    const float* __restrict__ xs,
    const _Float16* __restrict__ ax,
    const _Float16* __restrict__ ah,
    bool hvalid, int hcb, int lane,
    float* __restrict__ partsW) {
  const int quad = lane >> 4;
  H8 A[8];
#pragma unroll
  for (int c = 0; c < 8; ++c) {
    A[c].q[0] = 0ull;
    A[c].q[1] = 0ull;
    if (c < kccnt) {
      const int kc = kc0 + c;
      if (kc < hsplit) {
        if (xs) {
          const float* p = xs + kc * 32 + quad * 8;
          const float4 f0 = *(const float4*)p;
          const float4 f1 = *(const float4*)(p + 4);
          H8 t;
          t.h[0] = (_Float16)f0.x; t.h[1] = (_Float16)f0.y;
          t.h[2] = (_Float16)f0.z; t.h[3] = (_Float16)f0.w;
          t.h[4] = (_Float16)f1.x; t.h[5] = (_Float16)f1.y;
          t.h[6] = (_Float16)f1.z; t.h[7] = (_Float16)f1.w;
          A[c] = t;
        } else {
          const _Float16* p = ax + kc * 32 + quad * 8;
          A[c].q[0] = ald64(p);
          A[c].q[1] = ald64(p + 4);
        }
      } else if (hvalid) {
        const _Float16* p = ah + (kc - hsplit) * 32 + quad * 8;
        A[c].q[0] = ald64(p);
        A[c].q[1] = ald64(p + 4);
      }
    }
  }
  floatx4 ar = {0.f, 0.f, 0.f, 0.f};
  floatx4 az = ar, axn = ar, ahn = ar;
  const size_t lb = (size_t)lane * 16;
#pragma unroll
  for (int c = 0; c < 8; ++c) {
    if (c < kccnt) {
      const int kc = kc0 + c;
      const bool inH = (kc >= hsplit);
      if (!inH || hvalid) {
        {
          const char* b = wf + (size_t)(g0u + hcb * nk0 + kc) * 2048 + lb;
          H8 whi;
          whi.u4 = *(const uint4*)b;
          ar = MFMA(A[c].h, whi.h, ar);
        }
        {
          const char* b = wf + (size_t)(g1u + hcb * nk1 + kc) * 2048 + lb;
          H8 whi;
          whi.u4 = *(const uint4*)b;
          az = MFMA(A[c].h, whi.h, az);
        }
        if (!inH) {
          const char* b = wf + (size_t)(g2u + hcb * nk2 + kc) * 2048 + lb;
          H8 whi;
          whi.u4 = *(const uint4*)b;
          axn = MFMA(A[c].h, whi.h, axn);
        } else {
          const char* b = wf + (size_t)(g3u + hcb * nk3 + (kc - hsplit)) * 2048 + lb;
          H8 whi;
          whi.u4 = *(const uint4*)b;
          ahn = MFMA(A[c].h, whi.h, ahn);
        }
      }
    }
  }
  const int m = lane & 15;
#pragma unroll
  for (int i = 0; i < 4; ++i) {
    const int idx = (quad * 4 + i) * 16 + m;
    partsW[0 * 256 + idx] = ar[i];
    partsW[1 * 256 + idx] = az[i];
    partsW[2 * 256 + idx] = axn[i];
    partsW[3 * 256 + idx] = ahn[i];
  }
}

extern "C" __global__ void __launch_bounds__(256, 1) gru_ae_kernel(
    const float* __restrict__ x,
    const float* __restrict__ eW0i, const float* __restrict__ eW0h,
    const float* __restrict__ eb0i, const float* __restrict__ eb0h,
    const float* __restrict__ eW1i, const float* __restrict__ eW1h,
    const float* __restrict__ eb1i, const float* __restrict__ eb1h,
    const float* __restrict__ elW, const float* __restrict__ elb,
    const float* __restrict__ dW0i, const float* __restrict__ dW0h,
    const float* __restrict__ db0i, const float* __restrict__ db0h,
    const float* __restrict__ dW1i, const float* __restrict__ dW1h,
    const float* __restrict__ db1i, const float* __restrict__ db1h,
    const float* __restrict__ dlW, const float* __restrict__ dlb,
    float* __restrict__ out, char* __restrict__ ws) {
  const int tid = threadIdx.x, bid = blockIdx.x;
  const int lane = tid & 63, w = tid >> 6;
  const int quad = lane >> 4, m = lane & 15;
  const bool isP0 = bid < 128;
  const int pb = isP0 ? bid : bid - 128;
  const int rb = pb >> 5, hcb = pb & 31;

  int* flags = (int*)(ws + OFF_FLAGS);
  int* gep = (int*)(ws + OFF_GEP);
  float* zbuf = (float*)(ws + OFF_Z);
  float* gxc = (float*)(ws + OFF_GXC);
  _Float16* h0r = (_Float16*)(ws + OFF_H0);
  _Float16* h1r = (_Float16*)(ws + OFF_H1);
  _Float16* g0r = (_Float16*)(ws + OFF_G0);
  _Float16* g1r = (_Float16*)(ws + OFF_G1);
  _Float16* lWp = (_Float16*)(ws + OFF_LWP);
  const char* wfb = ws + OFF_WF;
  const char* wf0 = wfb;
  const char* wf1 = wfb + (size_t)1728 * 2048;
  const char* wf2 = wfb + (size_t)(1728 + 3072) * 2048;
  const char* wf3 = wfb + (size_t)(1728 + 3072 + 1536) * 2048;

  __shared__ float parts[4][4][256];
  __shared__ float outp[4][64];

  // per-thread epilogue state: wave w owns output row-slot i=w
  float hold_s = 0.f;
  float br = 0.f, bz = 0.f, bx = 0.f, bh = 0.f;
  float gxr_s = 0.f, gxz_s = 0.f, gxn_s = 0.f;

  for (int e = E_PREP; e <= E_LAST; ++e) {
    if (e > E_PREP) {
      if (w == 0) {
        if (bid == 0) {
          // root: gather all 256 flags, then publish the epoch counter.
          pollwait(flags, e - 1);
          __hip_atomic_store(gep, e - 1, __ATOMIC_RELEASE, SC_AGT);
        } else {
          pollwait_gep(gep, e - 1);
        }
      }
      __syncthreads();  // release other waves once w0 has seen the epoch
    }

    // ---------------- WORK (all waves) ----------------
    if (e == E_PREP) {
      // pack weights: fp16 hi/lo planes, MFMA-fragment ordered
      const int uend[4] = {1728, 4800, 6336, 9408};
      const int gub_[4][4] = {{0, 576, 1152, 1216}, {0, 1024, 2048, 2560},
                              {0, 512, 1024, 1024}, {0, 1024, 2048, 2560}};
      const int nkc_[4][4] = {{18, 18, 2, 16}, {32, 32, 16, 16},
                              {16, 16, 0, 16}, {32, 32, 16, 16}};
      const size_t wbL[4] = {0, (size_t)1728 * 2048, (size_t)4800 * 2048,
                             (size_t)6336 * 2048};
      const int wgid = bid * 4 + w;
      for (int unit = wgid; unit < 9408; unit += 1024) {
        int L = 0, lu = unit;
        if (unit >= uend[2]) { L = 3; lu = unit - uend[2]; }
        else if (unit >= uend[1]) { L = 2; lu = unit - uend[1]; }
        else if (unit >= uend[0]) { L = 1; lu = unit - uend[0]; }
        int g;
        if (lu < gub_[L][1]) g = 0;
        else if (lu < gub_[L][2]) g = 1;
        else if (nkc_[L][2] > 0 && lu < gub_[L][3]) g = 2;
        else g = 3;
        const int r2 = lu - gub_[L][g];
        const int nk = nkc_[L][g];
        const int hcbp = r2 / nk, kcp = r2 % nk;
        const int colp = hcbp * 16 + m;
        const float *Wi, *Wh;
        int Din;
        if (L == 0)      { Wi = eW0i; Wh = eW0h; Din = 64; }
        else if (L == 1) { Wi = eW1i; Wh = eW1h; Din = 512; }
        else if (L == 2) { Wi = nullptr; Wh = dW0h; Din = 0; }
        else             { Wi = dW1i; Wh = dW1h; Din = 512; }
        char* ub = (char*)(ws + OFF_WF) + wbL[L] + (size_t)lu * 2048 + lane * 16;
#pragma unroll
        for (int jj = 0; jj < 4; ++jj) {
          unsigned int hiw = 0, low = 0;
#pragma unroll
          for (int j2 = 0; j2 < 2; ++j2) {
            const int j = jj * 2 + j2;
            const int k = kcp * 32 + quad * 8 + j;
            float wv;
            if (g <= 1) {
              if (Wi && k < Din) wv = Wi[(size_t)(g * 512 + colp) * Din + k];
              else wv = Wh[(size_t)(g * 512 + colp) * 512 + (k - (Wi ? Din : 0))];
            } else if (g == 2) {
              wv = Wi[(size_t)(1024 + colp) * Din + k];
            } else {
              wv = Wh[(size_t)(1024 + colp) * 512 + k];
            }
            HU hi, lo;
            hi.f = (_Float16)wv;
            lo.f = (_Float16)(wv - (float)hi.f);
            hiw |= ((unsigned int)hi.u) << (16 * j2);
            low |= ((unsigned int)lo.u) << (16 * j2);
          }
          ast32u(ub + jj * 4, hiw);
          ast32u(ub + 1024 + jj * 4, low);
        }
      }
      // pack final-linear weight fp16
      const int gid = bid * 256 + tid;
      if (gid < 32768) {
        HU cv;
        cv.f = (_Float16)dlW[gid];
        ast16(lWp + gid, cv.u);
      }
    } else if (e <= E_ENC_END) {
      const int u = e - E_ENC_BEG;
      if (e == E_ENC_BEG) {
        const int colg = hcb * 16 + m;
        if (isP0) {
          br = eb0i[colg] + eb0h[colg];
          bz = eb0i[512 + colg] + eb0h[512 + colg];
          bx = eb0i[1024 + colg];
          bh = eb0h[1024 + colg];
        } else {
          br = eb1i[colg] + eb1h[colg];
          bz = eb1i[512 + colg] + eb1h[512 + colg];
          bx = eb1i[1024 + colg];
          bh = eb1h[1024 + colg];
        }
        hold_s = 0.f;
      }
      if (isP0) {
        if (u <= 1023) {
          const int t = u;
          const float* xs = x + ((size_t)t * 64 + rb * 16 + m) * 64;
          const _Float16* ah = h0r + (size_t)((t - 1) & 1) * 32768 + (rb * 16 + m) * 512;
          const int kc0 = (w == 0) ? 0 : (w == 1) ? 5 : (w == 2) ? 10 : 14;
          const int cnt = (w < 2) ? 5 : 4;
          tick_partials(wf0, 0, 576, 1152, 1216, 18, 18, 2, 16, kc0, cnt, 2,
                        xs, nullptr, ah, t >= 1, hcb, lane, &parts[w][0][0]);
        }
      } else {
        if (u >= 1) {
          const int t = u - 1;
          const _Float16* ax = h0r + (size_t)(t & 1) * 32768 + (rb * 16 + m) * 512;
          const _Float16* ah = h1r + (size_t)((t - 1) & 1) * 32768 + (rb * 16 + m) * 512;
          tick_partials(wf1, 0, 1024, 2048, 2560, 32, 32, 16, 16, w * 8, 8, 16,
                        nullptr, ax, ah, t >= 1, hcb, lane, &parts[w][0][0]);
        }
      }
    } else if (e == E_Z) {
      const int b = bid >> 2, e0 = (bid & 3) * 32;
      float acc = 0.f;
      if (lane < 32) {
        const _Float16* hsrc = h1r + (size_t)1 * 32768 + b * 512;  // h1[1023]
        const float* lwrow = elW + (size_t)(e0 + lane) * 512;
        for (int ch = 0; ch < 16; ++ch) {
          const int k = w * 128 + ch * 8;
          H8 a;
          a.q[0] = ald64(hsrc + k);
          a.q[1] = ald64(hsrc + k + 4);
          const float4 l0 = *(const float4*)(lwrow + k);
          const float4 l1 = *(const float4*)(lwrow + k + 4);
          acc += (float)a.h[0] * l0.x + (float)a.h[1] * l0.y +
                 (float)a.h[2] * l0.z + (float)a.h[3] * l0.w +
                 (float)a.h[4] * l1.x + (float)a.h[5] * l1.y +
                 (float)a.h[6] * l1.z + (float)a.h[7] * l1.w;
        }
      }
      outp[w][lane] = acc;
    } else if (e == E_GXC) {
      const int b = bid & 63, cb = (bid >> 6) * 384;
      for (int idx = w * 64 + lane; idx < 384; idx += 256) {
        const int c = cb + idx;
        float acc = db0i[c];
        const float* zr = zbuf + b * 128;
        const float* wr = dW0i + (size_t)c * 128;
        for (int k = 0; k < 128; ++k) acc += zr[k] * wr[k];
        astf(&gxc[(size_t)b * 1536 + c], acc);
      }
    } else {
      const int v = e - E_DEC_BEG;
      if (e == E_DEC_BEG) {
        const int colg = hcb * 16 + m;
        if (isP0) {
          br = db0h[colg];
          bz = db0h[512 + colg];
          bx = 0.f;
          bh = db0h[1024 + colg];
          // per-thread gx scalars for this thread's epilogue row (i = w)
          const int row0 = rb * 16 + quad * 4 + w;
          gxr_s = gxc[(size_t)row0 * 1536 + colg];
          gxz_s = gxc[(size_t)row0 * 1536 + 512 + colg];
          gxn_s = gxc[(size_t)row0 * 1536 + 1024 + colg];
        } else {
          br = db1i[colg] + db1h[colg];
          bz = db1i[512 + colg] + db1h[512 + colg];
          bx = db1i[1024 + colg];
          bh = db1h[1024 + colg];
        }
        hold_s = 0.f;
      }
      if (isP0) {
        if (v <= 1023) {
          const int t = v;
          const _Float16* ah = g0r + (size_t)((t - 1) & 1) * 32768 + (rb * 16 + m) * 512;
          tick_partials(wf2, 0, 512, 0, 1024, 16, 16, 0, 16, w * 4, 4, 0,
                        nullptr, nullptr, ah, t >= 1, hcb, lane, &parts[w][0][0]);
        }
        if (pb < 64 && v >= 2) {
          // final linear partials: out[t2][b=pb][i=lane], K split by wave
          const int t2 = v - 2;
          const _Float16* gsrc = g1r + (size_t)(t2 & 1) * 32768 + pb * 512;
          const _Float16* lrow = lWp + (size_t)lane * 512;
          float acc = 0.f;
          for (int ch = 0; ch < 16; ++ch) {
            const int k = w * 128 + ch * 8;
            H8 a, lw;
            a.q[0] = ald64(gsrc + k);
            a.q[1] = ald64(gsrc + k + 4);
            lw.u4 = *(const uint4*)(lrow + k);
#pragma unroll
            for (int j = 0; j < 8; ++j) acc += (float)a.h[j] * (float)lw.h[j];
          }
          outp[w][lane] = acc;
        }
      } else {
        if (v >= 1 && v <= 1024) {
          const int t = v - 1;
          const _Float16* ax = g0r + (size_t)(t & 1) * 32768 + (rb * 16 + m) * 512;
          const _Float16* ah = g1r + (size_t)((t - 1) & 1) * 32768 + (rb * 16 + m) * 512;
          tick_partials(wf3, 0, 1024, 2048, 2560, 32, 32, 16, 16, w * 8, 8, 16,
                        nullptr, ax, ah, t >= 1, hcb, lane, &parts[w][0][0]);
        }
      }
    }

    __syncthreads();  // bar1: all partials in LDS, all waves' stores drained

    // -------- EPILOGUE (all waves; wave w owns row-slot i=w) --------
    if (e >= E_ENC_BEG && e <= E_ENC_END) {
      const int u = e - E_ENC_BEG;
      const bool doep = isP0 ? (u <= 1023) : (u >= 1);
      if (doep) {
        const int idx = (quad * 4 + w) * 16 + m;
        const float sr = parts[0][0][idx] + parts[1][0][idx] +
                         parts[2][0][idx] + parts[3][0][idx];
        const float sz = parts[0][1][idx] + parts[1][1][idx] +
                         parts[2][1][idx] + parts[3][1][idx];
        const float sx = parts[0][2][idx] + parts[1][2][idx] +
                         parts[2][2][idx] + parts[3][2][idx];
        const float sh = parts[0][3][idx] + parts[1][3][idx] +
                         parts[2][3][idx] + parts[3][3][idx];
        const float r = sigm(sr + br);
        const float z = sigm(sz + bz);
        const float n = tanh_f(sx + bx + r * (sh + bh));
        const float hh = (1.f - z) * n + z * hold_s;
        hold_s = hh;
        _Float16* ring = isP0 ? (h0r + (size_t)(u & 1) * 32768)
                              : (h1r + (size_t)((u - 1) & 1) * 32768);
        HU cv;
        cv.f = (_Float16)hh;
        ast16(ring + (rb * 16 + quad * 4 + w) * 512 + hcb * 16 + m, cv.u);
      }
    } else if (e == E_Z) {
      if (w == 0 && lane < 32) {
        const int b = bid >> 2, e0 = (bid & 3) * 32;
        const float s = outp[0][lane] + outp[1][lane] + outp[2][lane] +
                        outp[3][lane] + elb[e0 + lane];
        astf(&zbuf[b * 128 + e0 + lane], s);
      }
    } else if (e >= E_DEC_BEG) {
      const int v = e - E_DEC_BEG;
      if (isP0) {
        if (v <= 1023) {
          const int idx = (quad * 4 + w) * 16 + m;
          const float sr = parts[0][0][idx] + parts[1][0][idx] +
                           parts[2][0][idx] + parts[3][0][idx];
          const float sz = parts[0][1][idx] + parts[1][1][idx] +
                           parts[2][1][idx] + parts[3][1][idx];
          const float sh = parts[0][3][idx] + parts[1][3][idx] +
                           parts[2][3][idx] + parts[3][3][idx];
          const float r = sigm(sr + gxr_s + br);
          const float z = sigm(sz + gxz_s + bz);
          const float n = tanh_f(gxn_s + r * (sh + bh));
          const float hh = (1.f - z) * n + z * hold_s;
          hold_s = hh;
          HU cv;
          cv.f = (_Float16)hh;
          ast16(g0r + (size_t)(v & 1) * 32768 +
                    (rb * 16 + quad * 4 + w) * 512 + hcb * 16 + m,
                cv.u);
        }
        if (w == 0 && pb < 64 && v >= 2) {
          const int t2 = v - 2;
          const float s = outp[0][lane] + outp[1][lane] + outp[2][lane] +
                          outp[3][lane] + dlb[lane];
          astf(&out[((size_t)t2 * 64 + pb) * 64 + lane], s);
        }
      } else {
        if (v >= 1 && v <= 1024) {
          const int idx = (quad * 4 + w) * 16 + m;
          const float sr = parts[0][0][idx] + parts[1][0][idx] +
                           parts[2][0][idx] + parts[3][0][idx];
          const float sz = parts[0][1][idx] + parts[1][1][idx] +
                           parts[2][1][idx] + parts[3][1][idx];
          const float sx = parts[0][2][idx] + parts[1][2][idx] +
                           parts[2][2][idx] + parts[3][2][idx];
          const float sh = parts[0][3][idx] + parts[1][3][idx] +
                           parts[2][3][idx] + parts[3][3][idx];
          const float r = sigm(sr + br);
          const float z = sigm(sz + bz);
          const float n = tanh_f(sx + bx + r * (sh + bh));
          const float hh = (1.f - z) * n + z * hold_s;
          hold_s = hh;
          HU cv;
          cv.f = (_Float16)hh;
          ast16(g1r + (size_t)((v - 1) & 1) * 32768 +
                    (rb * 16 + quad * 4 + w) * 512 + hcb * 16 + m,
                cv.u);
        }
      }
    }

    __syncthreads();  // bar2: drain ALL waves' epilogue stores + LDS reuse

    if (tid == 0) {
      // release: bar2's vmcnt-drain completed every wave's agent-scope ring
      // stores; this release-store publishes the epoch to the root.
      __hip_atomic_store(&flags[bid * 16], e, __ATOMIC_RELEASE, SC_AGT);
    }
  }
}

extern "C" void kernel_launch(void* const* d_in, const int* in_sizes, int n_in,
                              void* d_out, int out_size, void* d_ws, size_t ws_size,
                              hipStream_t stream) {
  (void)in_sizes; (void)n_in; (void)out_size; (void)ws_size;
  hipMemsetAsync(d_ws, 0, 16448, stream);  // zero flags + gepoch line
  hipLaunchKernelGGL(gru_ae_kernel, dim3(256), dim3(256), 0, stream,
                     (const float*)d_in[0],
                     (const float*)d_in[1], (const float*)d_in[2],
                     (const float*)d_in[3], (const float*)d_in[4],
                     (const float*)d_in[5], (const float*)d_in[6],
                     (const float*)d_in[7], (const float*)d_in[8],
                     (const float*)d_in[9], (const float*)d_in[10],
                     (const float*)d_in[11], (const float*)d_in[12],
                     (const float*)d_in[13], (const float*)d_in[14],
                     (const float*)d_in[15], (const float*)d_in[16],
                     (const float*)d_in[17], (const float*)d_in[18],
                     (const float*)d_in[19], (const float*)d_in[20],
                     (float*)d_out, (char*)d_ws);
}

// Round 11
// 14660.718 us; speedup vs baseline: 1.6064x; 1.2603x over previous
//
#include <hip/hip_runtime.h>

// ============================================================================
// GRU autoencoder, single persistent kernel, MI355X (gfx950).  Round 17:
// round-16 base (hi-plane-only weights, root-gep barrier, all-wave
// epilogue; verified 18.48 ms) with RELAXED epoch-flag publication:
//   - the per-epoch flag store and the root's gep store were agent-scope
//     RELEASE; a conservative lowering of agent-release on gfx950 must
//     write back the (non-coherent, per-XCD) L2 (buffer_wbl2) to publish
//     prior writes -- 256 blocks x 2054 epochs of L2-writeback scans is a
//     candidate for the ~5 us/epoch unexplained sync cost.
//   - RELAXED is sufficient here: all ring/data stores are ALREADY
//     agent-scope atomic stores (write-through to the coherence point --
//     proven by cross-XCD relaxed atomic loads observing them), and bar2's
//     __syncthreads drains vmcnt(0), guaranteeing completion before tid0's
//     flag store.  data@L3 -> flag@L3 -> root -> gep -> consumer reads L3.
//   - if this FAILS absmax, data stores were L2-dirty and the release's
//     writeback was load-bearing: revert to r16 and declare sync floor.
// ============================================================================

#define SC_AGT __HIP_MEMORY_SCOPE_AGENT

typedef _Float16 half8 __attribute__((ext_vector_type(8)));
typedef float floatx4 __attribute__((ext_vector_type(4)));

union H8 { unsigned long long q[2]; half8 h; uint4 u4; };
union HU { _Float16 f; unsigned short u; };

// ---- workspace layout (bytes) ----
static constexpr size_t OFF_FLAGS = 0;                        // 256 * 64B lines
static constexpr size_t OFF_GEP   = 16384;                    // 1 * 64B line
static constexpr size_t OFF_Z     = 16448;                    // 64*128*4
static constexpr size_t OFF_GXC   = OFF_Z + 64 * 128 * 4;     // 64*1536*4
static constexpr size_t OFF_H0    = OFF_GXC + 64 * 1536 * 4;  // 2*64*512*2 each
static constexpr size_t OFF_H1    = OFF_H0 + 2 * 64 * 512 * 2;
static constexpr size_t OFF_G0    = OFF_H1 + 2 * 64 * 512 * 2;
static constexpr size_t OFF_G1    = OFF_G0 + 2 * 64 * 512 * 2;
static constexpr size_t OFF_LWP   = OFF_G1 + 2 * 64 * 512 * 2; // 64*512*2
static constexpr size_t OFF_WF    = OFF_LWP + 64 * 512 * 2;
// W-fragment store: unit = (gate,hcb,kc) = 2KB (hi plane 1KB + lo plane 1KB)
// layer unit counts: L0 1728, L1 3072, L2 1536, L3 3072  (total ~18.4 MB)

static constexpr int E_PREP    = 1;
static constexpr int E_ENC_BEG = 2;     // u = e-2, u in [0,1024]
static constexpr int E_ENC_END = 1026;
static constexpr int E_Z       = 1027;
static constexpr int E_GXC     = 1028;
static constexpr int E_DEC_BEG = 1029;  // v = e-1029, v in [0,1025]
static constexpr int E_LAST    = 2054;

__device__ __forceinline__ unsigned long long ald64(const void* p) {
  return __hip_atomic_load((const unsigned long long*)p, __ATOMIC_RELAXED, SC_AGT);
}
__device__ __forceinline__ int ald32(const int* p) {
  return __hip_atomic_load(p, __ATOMIC_RELAXED, SC_AGT);
}
__device__ __forceinline__ void ast16(void* p, unsigned short v) {
  __hip_atomic_store((unsigned short*)p, v, __ATOMIC_RELAXED, SC_AGT);
}
__device__ __forceinline__ void ast32u(void* p, unsigned int v) {
  __hip_atomic_store((unsigned int*)p, v, __ATOMIC_RELAXED, SC_AGT);
}
__device__ __forceinline__ void astf(float* p, float v) {
  __hip_atomic_store(p, v, __ATOMIC_RELAXED, SC_AGT);
}

__device__ __forceinline__ float sigm(float x) { return 1.f / (1.f + __expf(-x)); }
__device__ __forceinline__ float tanh_f(float x) {
  x = fminf(fmaxf(x, -30.f), 30.f);
  const float e2 = __expf(2.f * x);
  return (e2 - 1.f) / (e2 + 1.f);
}

#define MFMA(a, b, c) __builtin_amdgcn_mfma_f32_16x16x32_f16((a), (b), (c), 0, 0, 0)

// root barrier wait (block 0, wave 0 only): lane i polls block flags i,
// i+64, i+128, i+192 -- each flag on its own 64B line (flags[bid*16]).
__device__ __forceinline__ void pollwait(const int* flags, int target) {
  const int lane = threadIdx.x & 63;
  for (;;) {
    const int v0 = ald32(flags + (size_t)lane * 16);
    const int v1 = ald32(flags + (size_t)(64 + lane) * 16);
    const int v2 = ald32(flags + (size_t)(128 + lane) * 16);
    const int v3 = ald32(flags + (size_t)(192 + lane) * 16);
    const bool ok = (v0 >= target) && (v1 >= target) && (v2 >= target) &&
                    (v3 >= target);
    if (__ballot(ok) == ~0ull) break;
    __builtin_amdgcn_s_sleep(2);
  }
  asm volatile("" ::: "memory");
}

// non-root barrier wait: poll the single global epoch counter (wave-uniform
// address -> one L3 request per wave per iteration).
__device__ __forceinline__ void pollwait_gep(const int* gep, int target) {
  for (;;) {
    if (ald32(gep) >= target) break;
    __builtin_amdgcn_s_sleep(1);
  }
  asm volatile("" ::: "memory");
}

// One GRU step partial-GEMM for this wave's K-slice.  Round-6-verbatim
// structure (INLINE weight loads) but HI-PLANE ONLY: one load + one MFMA
// per gate per kc (lo residual plane unread).
__device__ __forceinline__ void tick_partials(
    const char* __restrict__ wf,
    int g0u, int g1u, int g2u, int g3u,
    int nk0, int nk1, int nk2, int nk3,
    int kc0, int kccnt, int hsplit,
    const float* __restrict__ xs,
    const _Float16* __restrict__ ax,
    const _Float16* __restrict__ ah,
    bool hvalid, int hcb, int lane,
    float* __restrict__ partsW) {
  const int quad = lane >> 4;
  H8 A[8];
#pragma unroll
  for (int c = 0; c < 8; ++c) {
    A[c].q[0] = 0ull;
    A[c].q[1] = 0ull;
    if (c < kccnt) {
      const int kc = kc0 + c;
      if (kc < hsplit) {
        if (xs) {
          const float* p = xs + kc * 32 + quad * 8;
          const float4 f0 = *(const float4*)p;
          const float4 f1 = *(const float4*)(p + 4);
          H8 t;
          t.h[0] = (_Float16)f0.x; t.h[1] = (_Float16)f0.y;
          t.h[2] = (_Float16)f0.z; t.h[3] = (_Float16)f0.w;
          t.h[4] = (_Float16)f1.x; t.h[5] = (_Float16)f1.y;
          t.h[6] = (_Float16)f1.z; t.h[7] = (_Float16)f1.w;
          A[c] = t;
        } else {
          const _Float16* p = ax + kc * 32 + quad * 8;
          A[c].q[0] = ald64(p);
          A[c].q[1] = ald64(p + 4);
        }
      } else if (hvalid) {
        const _Float16* p = ah + (kc - hsplit) * 32 + quad * 8;
        A[c].q[0] = ald64(p);
        A[c].q[1] = ald64(p + 4);
      }
    }
  }
  floatx4 ar = {0.f, 0.f, 0.f, 0.f};
  floatx4 az = ar, axn = ar, ahn = ar;
  const size_t lb = (size_t)lane * 16;
#pragma unroll
  for (int c = 0; c < 8; ++c) {
    if (c < kccnt) {
      const int kc = kc0 + c;
      const bool inH = (kc >= hsplit);
      if (!inH || hvalid) {
        {
          const char* b = wf + (size_t)(g0u + hcb * nk0 + kc) * 2048 + lb;
          H8 whi;
          whi.u4 = *(const uint4*)b;
          ar = MFMA(A[c].h, whi.h, ar);
        }
        {
          const char* b = wf + (size_t)(g1u + hcb * nk1 + kc) * 2048 + lb;
          H8 whi;
          whi.u4 = *(const uint4*)b;
          az = MFMA(A[c].h, whi.h, az);
        }
        if (!inH) {
          const char* b = wf + (size_t)(g2u + hcb * nk2 + kc) * 2048 + lb;
          H8 whi;
          whi.u4 = *(const uint4*)b;
          axn = MFMA(A[c].h, whi.h, axn);
        } else {
          const char* b = wf + (size_t)(g3u + hcb * nk3 + (kc - hsplit)) * 2048 + lb;
          H8 whi;
          whi.u4 = *(const uint4*)b;
          ahn = MFMA(A[c].h, whi.h, ahn);
        }
      }
    }
  }
  const int m = lane & 15;
#pragma unroll
  for (int i = 0; i < 4; ++i) {
    const int idx = (quad * 4 + i) * 16 + m;
    partsW[0 * 256 + idx] = ar[i];
    partsW[1 * 256 + idx] = az[i];
    partsW[2 * 256 + idx] = axn[i];
    partsW[3 * 256 + idx] = ahn[i];
  }
}

extern "C" __global__ void __launch_bounds__(256, 1) gru_ae_kernel(
    const float* __restrict__ x,
    const float* __restrict__ eW0i, const float* __restrict__ eW0h,
    const float* __restrict__ eb0i, const float* __restrict__ eb0h,
    const float* __restrict__ eW1i, const float* __restrict__ eW1h,
    const float* __restrict__ eb1i, const float* __restrict__ eb1h,
    const float* __restrict__ elW, const float* __restrict__ elb,
    const float* __restrict__ dW0i, const float* __restrict__ dW0h,
    const float* __restrict__ db0i, const float* __restrict__ db0h,
    const float* __restrict__ dW1i, const float* __restrict__ dW1h,
    const float* __restrict__ db1i, const float* __restrict__ db1h,
    const float* __restrict__ dlW, const float* __restrict__ dlb,
    float* __restrict__ out, char* __restrict__ ws) {
  const int tid = threadIdx.x, bid = blockIdx.x;
  const int lane = tid & 63, w = tid >> 6;
  const int quad = lane >> 4, m = lane & 15;
  const bool isP0 = bid < 128;
  const int pb = isP0 ? bid : bid - 128;
  const int rb = pb >> 5, hcb = pb & 31;

  int* flags = (int*)(ws + OFF_FLAGS);
  int* gep = (int*)(ws + OFF_GEP);
  float* zbuf = (float*)(ws + OFF_Z);
  float* gxc = (float*)(ws + OFF_GXC);
  _Float16* h0r = (_Float16*)(ws + OFF_H0);
  _Float16* h1r = (_Float16*)(ws + OFF_H1);
  _Float16* g0r = (_Float16*)(ws + OFF_G0);
  _Float16* g1r = (_Float16*)(ws + OFF_G1);
  _Float16* lWp = (_Float16*)(ws + OFF_LWP);
  const char* wfb = ws + OFF_WF;
  const char* wf0 = wfb;
  const char* wf1 = wfb + (size_t)1728 * 2048;
  const char* wf2 = wfb + (size_t)(1728 + 3072) * 2048;
  const char* wf3 = wfb + (size_t)(1728 + 3072 + 1536) * 2048;

  __shared__ float parts[4][4][256];
  __shared__ float outp[4][64];

  // per-thread epilogue state: wave w owns output row-slot i=w
  float hold_s = 0.f;
  float br = 0.f, bz = 0.f, bx = 0.f, bh = 0.f;
  float gxr_s = 0.f, gxz_s = 0.f, gxn_s = 0.f;

  for (int e = E_PREP; e <= E_LAST; ++e) {
    if (e > E_PREP) {
      if (w == 0) {
        if (bid == 0) {
          // root: gather all 256 flags, then publish the epoch counter.
          pollwait(flags, e - 1);
          __hip_atomic_store(gep, e - 1, __ATOMIC_RELAXED, SC_AGT);
        } else {
          pollwait_gep(gep, e - 1);
        }
      }
      __syncthreads();  // release other waves once w0 has seen the epoch
    }

    // ---------------- WORK (all waves) ----------------
    if (e == E_PREP) {
      // pack weights: fp16 hi/lo planes, MFMA-fragment ordered
      const int uend[4] = {1728, 4800, 6336, 9408};
      const int gub_[4][4] = {{0, 576, 1152, 1216}, {0, 1024, 2048, 2560},
                              {0, 512, 1024, 1024}, {0, 1024, 2048, 2560}};
      const int nkc_[4][4] = {{18, 18, 2, 16}, {32, 32, 16, 16},
                              {16, 16, 0, 16}, {32, 32, 16, 16}};
      const size_t wbL[4] = {0, (size_t)1728 * 2048, (size_t)4800 * 2048,
                             (size_t)6336 * 2048};
      const int wgid = bid * 4 + w;
      for (int unit = wgid; unit < 9408; unit += 1024) {
        int L = 0, lu = unit;
        if (unit >= uend[2]) { L = 3; lu = unit - uend[2]; }
        else if (unit >= uend[1]) { L = 2; lu = unit - uend[1]; }
        else if (unit >= uend[0]) { L = 1; lu = unit - uend[0]; }
        int g;
        if (lu < gub_[L][1]) g = 0;
        else if (lu < gub_[L][2]) g = 1;
        else if (nkc_[L][2] > 0 && lu < gub_[L][3]) g = 2;
        else g = 3;
        const int r2 = lu - gub_[L][g];
        const int nk = nkc_[L][g];
        const int hcbp = r2 / nk, kcp = r2 % nk;
        const int colp = hcbp * 16 + m;
        const float *Wi, *Wh;
        int Din;
        if (L == 0)      { Wi = eW0i; Wh = eW0h; Din = 64; }
        else if (L == 1) { Wi = eW1i; Wh = eW1h; Din = 512; }
        else if (L == 2) { Wi = nullptr; Wh = dW0h; Din = 0; }
        else             { Wi = dW1i; Wh = dW1h; Din = 512; }
        char* ub = (char*)(ws + OFF_WF) + wbL[L] + (size_t)lu * 2048 + lane * 16;
#pragma unroll
        for (int jj = 0; jj < 4; ++jj) {
          unsigned int hiw = 0, low = 0;
#pragma unroll
          for (int j2 = 0; j2 < 2; ++j2) {
            const int j = jj * 2 + j2;
            const int k = kcp * 32 + quad * 8 + j;
            float wv;
            if (g <= 1) {
              if (Wi && k < Din) wv = Wi[(size_t)(g * 512 + colp) * Din + k];
              else wv = Wh[(size_t)(g * 512 + colp) * 512 + (k - (Wi ? Din : 0))];
            } else if (g == 2) {
              wv = Wi[(size_t)(1024 + colp) * Din + k];
            } else {
              wv = Wh[(size_t)(1024 + colp) * 512 + k];
            }
            HU hi, lo;
            hi.f = (_Float16)wv;
            lo.f = (_Float16)(wv - (float)hi.f);
            hiw |= ((unsigned int)hi.u) << (16 * j2);
            low |= ((unsigned int)lo.u) << (16 * j2);
          }
          ast32u(ub + jj * 4, hiw);
          ast32u(ub + 1024 + jj * 4, low);
        }
      }
      // pack final-linear weight fp16
      const int gid = bid * 256 + tid;
      if (gid < 32768) {
        HU cv;
        cv.f = (_Float16)dlW[gid];
        ast16(lWp + gid, cv.u);
      }
    } else if (e <= E_ENC_END) {
      const int u = e - E_ENC_BEG;
      if (e == E_ENC_BEG) {
        const int colg = hcb * 16 + m;
        if (isP0) {
          br = eb0i[colg] + eb0h[colg];
          bz = eb0i[512 + colg] + eb0h[512 + colg];
          bx = eb0i[1024 + colg];
          bh = eb0h[1024 + colg];
        } else {
          br = eb1i[colg] + eb1h[colg];
          bz = eb1i[512 + colg] + eb1h[512 + colg];
          bx = eb1i[1024 + colg];
          bh = eb1h[1024 + colg];
        }
        hold_s = 0.f;
      }
      if (isP0) {
        if (u <= 1023) {
          const int t = u;
          const float* xs = x + ((size_t)t * 64 + rb * 16 + m) * 64;
          const _Float16* ah = h0r + (size_t)((t - 1) & 1) * 32768 + (rb * 16 + m) * 512;
          const int kc0 = (w == 0) ? 0 : (w == 1) ? 5 : (w == 2) ? 10 : 14;
          const int cnt = (w < 2) ? 5 : 4;
          tick_partials(wf0, 0, 576, 1152, 1216, 18, 18, 2, 16, kc0, cnt, 2,
                        xs, nullptr, ah, t >= 1, hcb, lane, &parts[w][0][0]);
        }
      } else {
        if (u >= 1) {
          const int t = u - 1;
          const _Float16* ax = h0r + (size_t)(t & 1) * 32768 + (rb * 16 + m) * 512;
          const _Float16* ah = h1r + (size_t)((t - 1) & 1) * 32768 + (rb * 16 + m) * 512;
          tick_partials(wf1, 0, 1024, 2048, 2560, 32, 32, 16, 16, w * 8, 8, 16,
                        nullptr, ax, ah, t >= 1, hcb, lane, &parts[w][0][0]);
        }
      }
    } else if (e == E_Z) {
      const int b = bid >> 2, e0 = (bid & 3) * 32;
      float acc = 0.f;
      if (lane < 32) {
        const _Float16* hsrc = h1r + (size_t)1 * 32768 + b * 512;  // h1[1023]
        const float* lwrow = elW + (size_t)(e0 + lane) * 512;
        for (int ch = 0; ch < 16; ++ch) {
          const int k = w * 128 + ch * 8;
          H8 a;
          a.q[0] = ald64(hsrc + k);
          a.q[1] = ald64(hsrc + k + 4);
          const float4 l0 = *(const float4*)(lwrow + k);
          const float4 l1 = *(const float4*)(lwrow + k + 4);
          acc += (float)a.h[0] * l0.x + (float)a.h[1] * l0.y +
                 (float)a.h[2] * l0.z + (float)a.h[3] * l0.w +
                 (float)a.h[4] * l1.x + (float)a.h[5] * l1.y +
                 (float)a.h[6] * l1.z + (float)a.h[7] * l1.w;
        }
      }
      outp[w][lane] = acc;
    } else if (e == E_GXC) {
      const int b = bid & 63, cb = (bid >> 6) * 384;
      for (int idx = w * 64 + lane; idx < 384; idx += 256) {
        const int c = cb + idx;
        float acc = db0i[c];
        const float* zr = zbuf + b * 128;
        const float* wr = dW0i + (size_t)c * 128;
        for (int k = 0; k < 128; ++k) acc += zr[k] * wr[k];
        astf(&gxc[(size_t)b * 1536 + c], acc);
      }
    } else {
      const int v = e - E_DEC_BEG;
      if (e == E_DEC_BEG) {
        const int colg = hcb * 16 + m;
        if (isP0) {
          br = db0h[colg];
          bz = db0h[512 + colg];
          bx = 0.f;
          bh = db0h[1024 + colg];
          // per-thread gx scalars for this thread's epilogue row (i = w)
          const int row0 = rb * 16 + quad * 4 + w;
          gxr_s = gxc[(size_t)row0 * 1536 + colg];
          gxz_s = gxc[(size_t)row0 * 1536 + 512 + colg];
          gxn_s = gxc[(size_t)row0 * 1536 + 1024 + colg];
        } else {
          br = db1i[colg] + db1h[colg];
          bz = db1i[512 + colg] + db1h[512 + colg];
          bx = db1i[1024 + colg];
          bh = db1h[1024 + colg];
        }
        hold_s = 0.f;
      }
      if (isP0) {
        if (v <= 1023) {
          const int t = v;
          const _Float16* ah = g0r + (size_t)((t - 1) & 1) * 32768 + (rb * 16 + m) * 512;
          tick_partials(wf2, 0, 512, 0, 1024, 16, 16, 0, 16, w * 4, 4, 0,
                        nullptr, nullptr, ah, t >= 1, hcb, lane, &parts[w][0][0]);
        }
        if (pb < 64 && v >= 2) {
          // final linear partials: out[t2][b=pb][i=lane], K split by wave
          const int t2 = v - 2;
          const _Float16* gsrc = g1r + (size_t)(t2 & 1) * 32768 + pb * 512;
          const _Float16* lrow = lWp + (size_t)lane * 512;
          float acc = 0.f;
          for (int ch = 0; ch < 16; ++ch) {
            const int k = w * 128 + ch * 8;
            H8 a, lw;
            a.q[0] = ald64(gsrc + k);
            a.q[1] = ald64(gsrc + k + 4);
            lw.u4 = *(const uint4*)(lrow + k);
#pragma unroll
            for (int j = 0; j < 8; ++j) acc += (float)a.h[j] * (float)lw.h[j];
          }
          outp[w][lane] = acc;
        }
      } else {
        if (v >= 1 && v <= 1024) {
          const int t = v - 1;
          const _Float16* ax = g0r + (size_t)(t & 1) * 32768 + (rb * 16 + m) * 512;
          const _Float16* ah = g1r + (size_t)((t - 1) & 1) * 32768 + (rb * 16 + m) * 512;
          tick_partials(wf3, 0, 1024, 2048, 2560, 32, 32, 16, 16, w * 8, 8, 16,
                        nullptr, ax, ah, t >= 1, hcb, lane, &parts[w][0][0]);
        }
      }
    }

    __syncthreads();  // bar1: all partials in LDS, all waves' stores drained

    // -------- EPILOGUE (all waves; wave w owns row-slot i=w) --------
    if (e >= E_ENC_BEG && e <= E_ENC_END) {
      const int u = e - E_ENC_BEG;
      const bool doep = isP0 ? (u <= 1023) : (u >= 1);
      if (doep) {
        const int idx = (quad * 4 + w) * 16 + m;
        const float sr = parts[0][0][idx] + parts[1][0][idx] +
                         parts[2][0][idx] + parts[3][0][idx];
        const float sz = parts[0][1][idx] + parts[1][1][idx] +
                         parts[2][1][idx] + parts[3][1][idx];
        const float sx = parts[0][2][idx] + parts[1][2][idx] +
                         parts[2][2][idx] + parts[3][2][idx];
        const float sh = parts[0][3][idx] + parts[1][3][idx] +
                         parts[2][3][idx] + parts[3][3][idx];
        const float r = sigm(sr + br);
        const float z = sigm(sz + bz);
        const float n = tanh_f(sx + bx + r * (sh + bh));
        const float hh = (1.f - z) * n + z * hold_s;
        hold_s = hh;
        _Float16* ring = isP0 ? (h0r + (size_t)(u & 1) * 32768)
                              : (h1r + (size_t)((u - 1) & 1) * 32768);
        HU cv;
        cv.f = (_Float16)hh;
        ast16(ring + (rb * 16 + quad * 4 + w) * 512 + hcb * 16 + m, cv.u);
      }
    } else if (e == E_Z) {
      if (w == 0 && lane < 32) {
        const int b = bid >> 2, e0 = (bid & 3) * 32;
        const float s = outp[0][lane] + outp[1][lane] + outp[2][lane] +
                        outp[3][lane] + elb[e0 + lane];
        astf(&zbuf[b * 128 + e0 + lane], s);
      }
    } else if (e >= E_DEC_BEG) {
      const int v = e - E_DEC_BEG;
      if (isP0) {
        if (v <= 1023) {
          const int idx = (quad * 4 + w) * 16 + m;
          const float sr = parts[0][0][idx] + parts[1][0][idx] +
                           parts[2][0][idx] + parts[3][0][idx];
          const float sz = parts[0][1][idx] + parts[1][1][idx] +
                           parts[2][1][idx] + parts[3][1][idx];
          const float sh = parts[0][3][idx] + parts[1][3][idx] +
                           parts[2][3][idx] + parts[3][3][idx];
          const float r = sigm(sr + gxr_s + br);
          const float z = sigm(sz + gxz_s + bz);
          const float n = tanh_f(gxn_s + r * (sh + bh));
          const float hh = (1.f - z) * n + z * hold_s;
          hold_s = hh;
          HU cv;
          cv.f = (_Float16)hh;
          ast16(g0r + (size_t)(v & 1) * 32768 +
                    (rb * 16 + quad * 4 + w) * 512 + hcb * 16 + m,
                cv.u);
        }
        if (w == 0 && pb < 64 && v >= 2) {
          const int t2 = v - 2;
          const float s = outp[0][lane] + outp[1][lane] + outp[2][lane] +
                          outp[3][lane] + dlb[lane];
          astf(&out[((size_t)t2 * 64 + pb) * 64 + lane], s);
        }
      } else {
        if (v >= 1 && v <= 1024) {
          const int idx = (quad * 4 + w) * 16 + m;
          const float sr = parts[0][0][idx] + parts[1][0][idx] +
                           parts[2][0][idx] + parts[3][0][idx];
          const float sz = parts[0][1][idx] + parts[1][1][idx] +
                           parts[2][1][idx] + parts[3][1][idx];
          const float sx = parts[0][2][idx] + parts[1][2][idx] +
                           parts[2][2][idx] + parts[3][2][idx];
          const float sh = parts[0][3][idx] + parts[1][3][idx] +
                           parts[2][3][idx] + parts[3][3][idx];
          const float r = sigm(sr + br);
          const float z = sigm(sz + bz);
          const float n = tanh_f(sx + bx + r * (sh + bh));
          const float hh = (1.f - z) * n + z * hold_s;
          hold_s = hh;
          HU cv;
          cv.f = (_Float16)hh;
          ast16(g1r + (size_t)((v - 1) & 1) * 32768 +
                    (rb * 16 + quad * 4 + w) * 512 + hcb * 16 + m,
                cv.u);
        }
      }
    }

    __syncthreads();  // bar2: drain ALL waves' epilogue stores + LDS reuse

    if (tid == 0) {
      // relaxed publish: bar2's vmcnt-drain already completed every wave's
      // agent-scope (write-through) ring stores; no release/wbl2 needed.
      __hip_atomic_store(&flags[bid * 16], e, __ATOMIC_RELAXED, SC_AGT);
    }
  }
}

extern "C" void kernel_launch(void* const* d_in, const int* in_sizes, int n_in,
                              void* d_out, int out_size, void* d_ws, size_t ws_size,
                              hipStream_t stream) {
  (void)in_sizes; (void)n_in; (void)out_size; (void)ws_size;
  hipMemsetAsync(d_ws, 0, 16448, stream);  // zero flags + gepoch line
  hipLaunchKernelGGL(gru_ae_kernel, dim3(256), dim3(256), 0, stream,
                     (const float*)d_in[0],
                     (const float*)d_in[1], (const float*)d_in[2],
                     (const float*)d_in[3], (const float*)d_in[4],
                     (const float*)d_in[5], (const float*)d_in[6],
                     (const float*)d_in[7], (const float*)d_in[8],
                     (const float*)d_in[9], (const float*)d_in[10],
                     (const float*)d_in[11], (const float*)d_in[12],
                     (const float*)d_in[13], (const float*)d_in[14],
                     (const float*)d_in[15], (const float*)d_in[16],
                     (const float*)d_in[17], (const float*)d_in[18],
                     (const float*)d_in[19], (const float*)d_in[20],
                     (float*)d_out, (char*)d_ws);
}